// Round 1
// baseline (582.499 us; speedup 1.0000x reference)
//
#include <hip/hip_runtime.h>
#include <hip/hip_bf16.h>
#include <math.h>

#define BB 8
#define NN 2048
#define DD 1024
#define LL 128
#define MM (BB*NN)   // 16384

// ---------------- generic wave-per-output row dot: out[r,d] = sum_e X[r,e]*W[d,e]
__global__ __launch_bounds__(256) void linear_rowdot(const float* __restrict__ X,
                                                     const float* __restrict__ W,
                                                     float* __restrict__ out, int R) {
    int wid  = (blockIdx.x * blockDim.x + threadIdx.x) >> 6;
    int lane = threadIdx.x & 63;
    if (wid >= R * DD) return;
    int r = wid >> 10;        // / DD
    int d = wid & (DD - 1);
    const float* x = X + (size_t)r * DD;
    const float* w = W + (size_t)d * DD;
    float s = 0.f;
    for (int e = lane; e < DD; e += 64) s += x[e] * w[e];
    #pragma unroll
    for (int off = 32; off; off >>= 1) s += __shfl_down(s, off, 64);
    if (lane == 0) out[wid] = s;
}

// ---------------- heavy kernel: k_j tile GEMM + fused tanh(q+k)*omega row-reduction
// grid: (MM/64, DD/128); per block: 64 rows x 128 cols, full K=1024 loop.
#define Bb_M 64
#define Bb_D 128
#define Bb_K 16
__global__ __launch_bounds__(256) void sigma_gemm(const float* __restrict__ ej,   // [MM, DD]
                                                  const float* __restrict__ Wk,   // [DD, DD]
                                                  const float* __restrict__ q,    // [BB, DD]
                                                  const float* __restrict__ omega,// [DD]
                                                  float* __restrict__ sig_part)   // [8][MM]
{
    __shared__ float As[Bb_K][Bb_M];
    __shared__ float Bs[Bb_K][Bb_D];
    __shared__ float red[Bb_M][17];

    const int mblk = blockIdx.x;          // 0..255
    const int dblk = blockIdx.y;          // 0..7
    const int row0 = mblk * Bb_M;
    const int col0 = dblk * Bb_D;
    const int b    = row0 / NN;           // 64 | 2048 -> single b per block
    const int tid  = threadIdx.x;
    const int tx   = tid & 15;            // col group (8 cols)
    const int ty   = tid >> 4;            // row group (4 rows)

    float acc[4][8];
    #pragma unroll
    for (int i = 0; i < 4; ++i)
        #pragma unroll
        for (int j = 0; j < 8; ++j) acc[i][j] = 0.f;

    // staging index precompute
    const int ar = tid >> 2;              // 0..63
    const int ak = (tid & 3) * 4;         // 0,4,8,12
    const int bc = tid >> 1;              // 0..127
    const int bk = (tid & 1) * 8;         // 0,8

    for (int k0 = 0; k0 < DD; k0 += Bb_K) {
        {
            float4 v = *(const float4*)&ej[(size_t)(row0 + ar) * DD + k0 + ak];
            As[ak + 0][ar] = v.x; As[ak + 1][ar] = v.y;
            As[ak + 2][ar] = v.z; As[ak + 3][ar] = v.w;
        }
        {
            const float* src = &Wk[(size_t)(col0 + bc) * DD + k0 + bk];
            float4 v0 = *(const float4*)(src);
            float4 v1 = *(const float4*)(src + 4);
            Bs[bk + 0][bc] = v0.x; Bs[bk + 1][bc] = v0.y;
            Bs[bk + 2][bc] = v0.z; Bs[bk + 3][bc] = v0.w;
            Bs[bk + 4][bc] = v1.x; Bs[bk + 5][bc] = v1.y;
            Bs[bk + 6][bc] = v1.z; Bs[bk + 7][bc] = v1.w;
        }
        __syncthreads();
        #pragma unroll
        for (int kk = 0; kk < Bb_K; ++kk) {
            float a[4], bb[8];
            #pragma unroll
            for (int i = 0; i < 4; ++i) a[i] = As[kk][ty * 4 + i];
            #pragma unroll
            for (int j = 0; j < 8; ++j) bb[j] = Bs[kk][tx * 8 + j];
            #pragma unroll
            for (int i = 0; i < 4; ++i)
                #pragma unroll
                for (int j = 0; j < 8; ++j) acc[i][j] += a[i] * bb[j];
        }
        __syncthreads();
    }

    // epilogue: partial sigma over this block's 128 cols
    float part[4] = {0.f, 0.f, 0.f, 0.f};
    #pragma unroll
    for (int j = 0; j < 8; ++j) {
        int d = col0 + tx * 8 + j;
        float qv = q[b * DD + d];
        float om = omega[d];
        #pragma unroll
        for (int i = 0; i < 4; ++i)
            part[i] += tanhf(acc[i][j] + qv) * om;
    }
    #pragma unroll
    for (int i = 0; i < 4; ++i) red[ty * 4 + i][tx] = part[i];
    __syncthreads();
    if (tid < Bb_M) {
        float s = 0.f;
        #pragma unroll
        for (int t = 0; t < 16; ++t) s += red[tid][t];
        sig_part[dblk * MM + row0 + tid] = s;
    }
}

// ---------------- per-b softmax-style weights: a_ij = imp * exp(s)/(sum_exp + 1e-9)
__global__ __launch_bounds__(256) void softmax_k(const float* __restrict__ sig_part,
                                                 const float* __restrict__ imp,
                                                 float* __restrict__ a_ij) {
    int b = blockIdx.x;
    int tid = threadIdx.x;
    __shared__ float sbuf[NN];
    __shared__ float red[256];
    float m = -1e30f;
    for (int n = tid; n < NN; n += 256) {
        float s = 0.f;
        #pragma unroll
        for (int db = 0; db < 8; ++db) s += sig_part[db * MM + b * NN + n];
        sbuf[n] = s;
        m = fmaxf(m, s);
    }
    red[tid] = m; __syncthreads();
    for (int off = 128; off; off >>= 1) {
        if (tid < off) red[tid] = fmaxf(red[tid], red[tid + off]);
        __syncthreads();
    }
    m = red[0]; __syncthreads();
    float sum = 0.f;
    for (int n = tid; n < NN; n += 256) sum += expf(sbuf[n] - m);
    red[tid] = sum; __syncthreads();
    for (int off = 128; off; off >>= 1) {
        if (tid < off) red[tid] += red[tid + off];
        __syncthreads();
    }
    sum = red[0];
    // a = imp*exp(s)/(sum_exp+1e-9) = imp*exp(s-m)/(sum_exp*e^-m + 1e-9*e^-m)
    float denom = sum + 1e-9f * expf(-m);
    float inv = 1.f / denom;
    for (int n = tid; n < NN; n += 256)
        a_ij[b * NN + n] = imp[b * NN + n] * expf(sbuf[n] - m) * inv;
}

// ---------------- u[b,e] = sum_n a_ij[b,n] * e_j[b,n,e]  (atomic partial over n-chunks)
__global__ __launch_bounds__(256) void u_kernel(const float* __restrict__ a_ij,
                                                const float* __restrict__ ej,
                                                float* __restrict__ u) {
    int b = blockIdx.x, nc = blockIdx.y;
    int t = threadIdx.x;
    float4 acc = {0.f, 0.f, 0.f, 0.f};
    const float* base = ej + ((size_t)(b * NN + nc * 128)) * DD + t * 4;
    const float* ap = a_ij + b * NN + nc * 128;
    for (int n = 0; n < 128; ++n) {
        float a = ap[n];
        float4 v = *(const float4*)(base + (size_t)n * DD);
        acc.x += a * v.x; acc.y += a * v.y; acc.z += a * v.z; acc.w += a * v.w;
    }
    float* up = u + b * DD + t * 4;
    atomicAdd(up + 0, acc.x); atomicAdd(up + 1, acc.y);
    atomicAdd(up + 2, acc.z); atomicAdd(up + 3, acc.w);
}

// ---------------- outputs: A, A_lk = A*R, A_l = A
__global__ __launch_bounds__(256) void out_kernel(const float* __restrict__ A,
                                                  const float* __restrict__ Rlk,
                                                  float* __restrict__ out) {
    int i = blockIdx.x * 256 + threadIdx.x;    // < BB*LL*DD = 2^20
    int d = i & (DD - 1);
    int l = (i >> 10) & (LL - 1);
    int b = i >> 17;
    out[BB * DD + i] = A[b * DD + d] * Rlk[l * DD + d];
    if (i < BB * DD) {
        out[i] = A[i];
        out[BB * DD + BB * LL * DD + i] = A[i];
    }
}

extern "C" void kernel_launch(void* const* d_in, const int* in_sizes, int n_in,
                              void* d_out, int out_size, void* d_ws, size_t ws_size,
                              hipStream_t stream) {
    const float* e_i   = (const float*)d_in[0];
    const float* e_j   = (const float*)d_in[1];
    const float* imp   = (const float*)d_in[2];
    const float* Rlk   = (const float*)d_in[3];
    const float* Wq    = (const float*)d_in[4];
    const float* Wk    = (const float*)d_in[5];
    const float* Wv    = (const float*)d_in[6];
    const float* omega = (const float*)d_in[7];
    float* out = (float*)d_out;
    float* ws  = (float*)d_ws;

    float* q    = ws;               // 8192
    float* sigp = ws + 8192;        // 8*16384 = 131072
    float* a_ij = ws + 139264;      // 16384
    float* u    = ws + 155648;      // 8192
    float* Abuf = ws + 163840;      // 8192

    hipMemsetAsync(u, 0, BB * DD * sizeof(float), stream);

    // q = e_i @ Wq^T : 8*1024 outputs, wave each -> 2048 blocks
    linear_rowdot<<<2048, 256, 0, stream>>>(e_i, Wq, q, BB);

    // sigma partials (heavy GEMM + fused tanh reduce)
    sigma_gemm<<<dim3(MM / Bb_M, DD / Bb_D), 256, 0, stream>>>(e_j, Wk, q, omega, sigp);

    // a_ij
    softmax_k<<<BB, 256, 0, stream>>>(sigp, imp, a_ij);

    // u = a_ij-weighted sum of e_j rows
    u_kernel<<<dim3(BB, 16), 256, 0, stream>>>(a_ij, e_j, u);

    // A = u @ Wv^T
    linear_rowdot<<<2048, 256, 0, stream>>>(u, Wv, Abuf, BB);

    // outputs
    out_kernel<<<(BB * LL * DD) / 256, 256, 0, stream>>>(Abuf, Rlk, out);
}

// Round 2
// 277.971 us; speedup vs baseline: 2.0955x; 2.0955x over previous
//
#include <hip/hip_runtime.h>
#include <hip/hip_bf16.h>
#include <math.h>

#define BB 8
#define NN 2048
#define DD 1024
#define LL 128
#define MM (BB*NN)   // 16384

typedef __attribute__((ext_vector_type(8))) short short8;
typedef __attribute__((ext_vector_type(8))) unsigned short ushort8;
typedef __attribute__((ext_vector_type(4))) float floatx4;

__device__ __forceinline__ void glds16(const void* g, void* l) {
    __builtin_amdgcn_global_load_lds(
        (const __attribute__((address_space(1))) unsigned int*)g,
        (__attribute__((address_space(3))) unsigned int*)l, 16, 0, 0);
}

// ---------------- fp32 -> bf16 hi/lo split (RNE), 8 elements per thread
__global__ __launch_bounds__(256) void split_bf16(const float* __restrict__ x,
                                                  unsigned short* __restrict__ hi,
                                                  unsigned short* __restrict__ lo,
                                                  int n8) {
    int i = blockIdx.x * 256 + threadIdx.x;
    if (i >= n8) return;
    const float4* xp = (const float4*)x + (size_t)i * 2;
    float4 v0 = xp[0], v1 = xp[1];
    float f[8] = {v0.x, v0.y, v0.z, v0.w, v1.x, v1.y, v1.z, v1.w};
    ushort8 h, l;
    #pragma unroll
    for (int e = 0; e < 8; ++e) {
        unsigned u = __float_as_uint(f[e]);
        unsigned r = u + 0x7FFFu + ((u >> 16) & 1u);
        unsigned short hb = (unsigned short)(r >> 16);
        float hf = __uint_as_float((unsigned)hb << 16);
        float res = f[e] - hf;
        unsigned u2 = __float_as_uint(res);
        unsigned r2 = u2 + 0x7FFFu + ((u2 >> 16) & 1u);
        h[e] = hb;
        l[e] = (unsigned short)(r2 >> 16);
    }
    *(ushort8*)(hi + (size_t)i * 8) = h;
    *(ushort8*)(lo + (size_t)i * 8) = l;
}

// ---------------- generic wave-per-output row dot: out[r,d] = sum_e X[r,e]*W[d,e]
__global__ __launch_bounds__(256) void linear_rowdot(const float* __restrict__ X,
                                                     const float* __restrict__ W,
                                                     float* __restrict__ out, int R) {
    int wid  = (blockIdx.x * blockDim.x + threadIdx.x) >> 6;
    int lane = threadIdx.x & 63;
    if (wid >= R * DD) return;
    int r = wid >> 10;
    int d = wid & (DD - 1);
    const float* x = X + (size_t)r * DD;
    const float* w = W + (size_t)d * DD;
    float s = 0.f;
    for (int e = lane; e < DD; e += 64) s += x[e] * w[e];
    #pragma unroll
    for (int off = 32; off; off >>= 1) s += __shfl_down(s, off, 64);
    if (lane == 0) out[wid] = s;
}

// ---------------- heavy kernel: bf16x3 MFMA GEMM + fused tanh(q+k)*omega row-reduce
// 128x128 tile, BK=32, 4 waves in 2x2, each wave 64x64 via 4x4 of 16x16x32 MFMA.
__global__ __launch_bounds__(256) void sigma_mfma(const unsigned short* __restrict__ ehi,
                                                  const unsigned short* __restrict__ elo,
                                                  const unsigned short* __restrict__ wh,
                                                  const unsigned short* __restrict__ wl,
                                                  const float* __restrict__ q,
                                                  const float* __restrict__ omega,
                                                  float* __restrict__ sig_part)   // [8][MM]
{
    __shared__ unsigned short lds[4][128][32];   // Ahi, Alo, Bhi, Blo tiles (8KB each)
    __shared__ float red[128][2];

    const int tid  = threadIdx.x;
    const int lane = tid & 63;
    const int w    = tid >> 6;
    const int wr   = w >> 1, wc = w & 1;
    const int c15  = lane & 15, quad = lane >> 4;

    const int row0 = blockIdx.x * 128;
    const int col0 = blockIdx.y * 128;
    const int b    = row0 / NN;

    // staging source addresses: thread tid loads 16B at LDS byte tid*16 of each half-tile
    const int r0 = tid >> 2;            // row within half (0..63)
    const int kk = (tid & 3) * 8;       // k offset in shorts (0,8,16,24)

    const unsigned short* ga0 = ehi + (size_t)(row0 + r0) * DD + kk;
    const unsigned short* ga1 = ga0 + (size_t)64 * DD;
    const unsigned short* gb0 = elo + (size_t)(row0 + r0) * DD + kk;
    const unsigned short* gb1 = gb0 + (size_t)64 * DD;
    const unsigned short* gc0 = wh  + (size_t)(col0 + r0) * DD + kk;
    const unsigned short* gc1 = gc0 + (size_t)64 * DD;
    const unsigned short* gd0 = wl  + (size_t)(col0 + r0) * DD + kk;
    const unsigned short* gd1 = gd0 + (size_t)64 * DD;

    char* lbase = (char*)&lds[0][0][0] + w * 1024;

    floatx4 acc[4][4];
    #pragma unroll
    for (int i = 0; i < 4; ++i)
        #pragma unroll
        for (int j = 0; j < 4; ++j)
            acc[i][j] = (floatx4){0.f, 0.f, 0.f, 0.f};

    for (int k0 = 0; k0 < DD; k0 += 32) {
        glds16(ga0 + k0, lbase + 0 * 4096);
        glds16(ga1 + k0, lbase + 1 * 4096);
        glds16(gb0 + k0, lbase + 2 * 4096);
        glds16(gb1 + k0, lbase + 3 * 4096);
        glds16(gc0 + k0, lbase + 4 * 4096);
        glds16(gc1 + k0, lbase + 5 * 4096);
        glds16(gd0 + k0, lbase + 6 * 4096);
        glds16(gd1 + k0, lbase + 7 * 4096);
        __syncthreads();

        short8 ah[4], al[4], bh[4], bl[4];
        #pragma unroll
        for (int i = 0; i < 4; ++i) {
            ah[i] = *(const short8*)&lds[0][wr * 64 + i * 16 + c15][quad * 8];
            al[i] = *(const short8*)&lds[1][wr * 64 + i * 16 + c15][quad * 8];
            bh[i] = *(const short8*)&lds[2][wc * 64 + i * 16 + c15][quad * 8];
            bl[i] = *(const short8*)&lds[3][wc * 64 + i * 16 + c15][quad * 8];
        }
        #pragma unroll
        for (int i = 0; i < 4; ++i)
            #pragma unroll
            for (int j = 0; j < 4; ++j) {
                acc[i][j] = __builtin_amdgcn_mfma_f32_16x16x32_bf16(ah[i], bh[j], acc[i][j], 0, 0, 0);
                acc[i][j] = __builtin_amdgcn_mfma_f32_16x16x32_bf16(al[i], bh[j], acc[i][j], 0, 0, 0);
                acc[i][j] = __builtin_amdgcn_mfma_f32_16x16x32_bf16(ah[i], bl[j], acc[i][j], 0, 0, 0);
            }
        __syncthreads();
    }

    // epilogue: sigma partial per row over this block's 128 cols
    float part[4][4];   // [i][r]
    #pragma unroll
    for (int i = 0; i < 4; ++i)
        #pragma unroll
        for (int r = 0; r < 4; ++r) part[i][r] = 0.f;

    #pragma unroll
    for (int j = 0; j < 4; ++j) {
        int c = col0 + wc * 64 + j * 16 + c15;
        float qv = q[b * DD + c];
        float om = omega[c];
        #pragma unroll
        for (int i = 0; i < 4; ++i)
            #pragma unroll
            for (int r = 0; r < 4; ++r)
                part[i][r] += tanhf(acc[i][j][r] + qv) * om;
    }
    #pragma unroll
    for (int i = 0; i < 4; ++i)
        #pragma unroll
        for (int r = 0; r < 4; ++r) {
            float s = part[i][r];
            s += __shfl_xor(s, 1, 64);
            s += __shfl_xor(s, 2, 64);
            s += __shfl_xor(s, 4, 64);
            s += __shfl_xor(s, 8, 64);
            if (c15 == 0) red[wr * 64 + i * 16 + quad * 4 + r][wc] = s;
        }
    __syncthreads();
    if (tid < 128)
        sig_part[blockIdx.y * MM + row0 + tid] = red[tid][0] + red[tid][1];
}

// ---------------- per-b softmax-style weights
__global__ __launch_bounds__(256) void softmax_k(const float* __restrict__ sig_part,
                                                 const float* __restrict__ imp,
                                                 float* __restrict__ a_ij) {
    int b = blockIdx.x;
    int tid = threadIdx.x;
    __shared__ float sbuf[NN];
    __shared__ float red[256];
    float m = -1e30f;
    for (int n = tid; n < NN; n += 256) {
        float s = 0.f;
        #pragma unroll
        for (int db = 0; db < 8; ++db) s += sig_part[db * MM + b * NN + n];
        sbuf[n] = s;
        m = fmaxf(m, s);
    }
    red[tid] = m; __syncthreads();
    for (int off = 128; off; off >>= 1) {
        if (tid < off) red[tid] = fmaxf(red[tid], red[tid + off]);
        __syncthreads();
    }
    m = red[0]; __syncthreads();
    float sum = 0.f;
    for (int n = tid; n < NN; n += 256) sum += expf(sbuf[n] - m);
    red[tid] = sum; __syncthreads();
    for (int off = 128; off; off >>= 1) {
        if (tid < off) red[tid] += red[tid + off];
        __syncthreads();
    }
    sum = red[0];
    float denom = sum + 1e-9f * expf(-m);
    float inv = 1.f / denom;
    for (int n = tid; n < NN; n += 256)
        a_ij[b * NN + n] = imp[b * NN + n] * expf(sbuf[n] - m) * inv;
}

// ---------------- u[b,e] = sum_n a_ij[b,n] * e_j[b,n,e]
__global__ __launch_bounds__(256) void u_kernel(const float* __restrict__ a_ij,
                                                const float* __restrict__ ej,
                                                float* __restrict__ u) {
    int b = blockIdx.x, nc = blockIdx.y;
    int t = threadIdx.x;
    float4 acc = {0.f, 0.f, 0.f, 0.f};
    const float* base = ej + ((size_t)(b * NN + nc * 128)) * DD + t * 4;
    const float* ap = a_ij + b * NN + nc * 128;
    for (int n = 0; n < 128; ++n) {
        float a = ap[n];
        float4 v = *(const float4*)(base + (size_t)n * DD);
        acc.x += a * v.x; acc.y += a * v.y; acc.z += a * v.z; acc.w += a * v.w;
    }
    float* up = u + b * DD + t * 4;
    atomicAdd(up + 0, acc.x); atomicAdd(up + 1, acc.y);
    atomicAdd(up + 2, acc.z); atomicAdd(up + 3, acc.w);
}

// ---------------- outputs: A, A_lk = A*R, A_l = A
__global__ __launch_bounds__(256) void out_kernel(const float* __restrict__ A,
                                                  const float* __restrict__ Rlk,
                                                  float* __restrict__ out) {
    int i = blockIdx.x * 256 + threadIdx.x;
    int d = i & (DD - 1);
    int l = (i >> 10) & (LL - 1);
    int b = i >> 17;
    out[BB * DD + i] = A[b * DD + d] * Rlk[l * DD + d];
    if (i < BB * DD) {
        out[i] = A[i];
        out[BB * DD + BB * LL * DD + i] = A[i];
    }
}

extern "C" void kernel_launch(void* const* d_in, const int* in_sizes, int n_in,
                              void* d_out, int out_size, void* d_ws, size_t ws_size,
                              hipStream_t stream) {
    const float* e_i   = (const float*)d_in[0];
    const float* e_j   = (const float*)d_in[1];
    const float* imp   = (const float*)d_in[2];
    const float* Rlk   = (const float*)d_in[3];
    const float* Wq    = (const float*)d_in[4];
    const float* Wk    = (const float*)d_in[5];
    const float* Wv    = (const float*)d_in[6];
    const float* omega = (const float*)d_in[7];
    float* out = (float*)d_out;
    float* ws  = (float*)d_ws;

    float* q    = ws;               // 8192
    float* sigp = ws + 8192;        // 131072
    float* a_ij = ws + 139264;      // 16384
    float* u    = ws + 155648;      // 8192
    float* Abuf = ws + 163840;      // 8192
    unsigned short* ehi = (unsigned short*)(ws + 172032);  // MM*DD shorts
    unsigned short* elo = ehi + (size_t)MM * DD;
    unsigned short* wh  = elo + (size_t)MM * DD;
    unsigned short* wl  = wh + (size_t)DD * DD;

    hipMemsetAsync(u, 0, BB * DD * sizeof(float), stream);

    // bf16 hi/lo split of e_j and W_k
    split_bf16<<<(MM * DD / 8) / 256, 256, 0, stream>>>(e_j, ehi, elo, MM * DD / 8);
    split_bf16<<<(DD * DD / 8) / 256, 256, 0, stream>>>(Wk, wh, wl, DD * DD / 8);

    // q = e_i @ Wq^T
    linear_rowdot<<<2048, 256, 0, stream>>>(e_i, Wq, q, BB);

    // sigma partials: bf16x3 MFMA GEMM with fused tanh-omega reduction
    sigma_mfma<<<dim3(MM / 128, DD / 128), 256, 0, stream>>>(ehi, elo, wh, wl, q, omega, sigp);

    // a_ij
    softmax_k<<<BB, 256, 0, stream>>>(sigp, imp, a_ij);

    // u = a_ij-weighted sum of e_j rows
    u_kernel<<<dim3(BB, 16), 256, 0, stream>>>(a_ij, e_j, u);

    // A = u @ Wv^T
    linear_rowdot<<<2048, 256, 0, stream>>>(u, Wv, Abuf, BB);

    // outputs
    out_kernel<<<(BB * LL * DD) / 256, 256, 0, stream>>>(Abuf, Rlk, out);
}

// Round 3
// 276.091 us; speedup vs baseline: 2.1098x; 1.0068x over previous
//
#include <hip/hip_runtime.h>
#include <hip/hip_bf16.h>
#include <math.h>

#define BB 8
#define NN 2048
#define DD 1024
#define LL 128
#define MM (BB*NN)   // 16384

typedef __attribute__((ext_vector_type(8))) short short8;
typedef __attribute__((ext_vector_type(8))) unsigned short ushort8;
typedef __attribute__((ext_vector_type(4))) float floatx4;

__device__ __forceinline__ void glds16(const void* g, void* l) {
    __builtin_amdgcn_global_load_lds(
        (const __attribute__((address_space(1))) unsigned int*)g,
        (__attribute__((address_space(3))) unsigned int*)l, 16, 0, 0);
}

// fp32 -> bf16 hi/lo split (RNE) of 8 consecutive elements at index i*8
__device__ __forceinline__ void split8(const float* __restrict__ x,
                                       unsigned short* __restrict__ hi,
                                       unsigned short* __restrict__ lo, int i) {
    const float4* xp = (const float4*)x + (size_t)i * 2;
    float4 v0 = xp[0], v1 = xp[1];
    float f[8] = {v0.x, v0.y, v0.z, v0.w, v1.x, v1.y, v1.z, v1.w};
    ushort8 h, l;
    #pragma unroll
    for (int e = 0; e < 8; ++e) {
        unsigned u = __float_as_uint(f[e]);
        unsigned r = u + 0x7FFFu + ((u >> 16) & 1u);
        unsigned short hb = (unsigned short)(r >> 16);
        float hf = __uint_as_float((unsigned)hb << 16);
        float res = f[e] - hf;
        unsigned u2 = __float_as_uint(res);
        unsigned r2 = u2 + 0x7FFFu + ((u2 >> 16) & 1u);
        h[e] = hb;
        l[e] = (unsigned short)(r2 >> 16);
    }
    *(ushort8*)(hi + (size_t)i * 8) = h;
    *(ushort8*)(lo + (size_t)i * 8) = l;
}

// ---------------- fused preprocessing: split(e_j), split(Wk), q = e_i @ Wq^T
// blocks [0,8192): e_j split; [8192,8704): Wk split; [8704,10752): q rowdot
__global__ __launch_bounds__(256) void prep_kernel(const float* __restrict__ e_j,
                                                   unsigned short* __restrict__ ehi,
                                                   unsigned short* __restrict__ elo,
                                                   const float* __restrict__ Wk,
                                                   unsigned short* __restrict__ wh,
                                                   unsigned short* __restrict__ wl,
                                                   const float* __restrict__ e_i,
                                                   const float* __restrict__ Wq,
                                                   float* __restrict__ q) {
    int blk = blockIdx.x;
    int tid = threadIdx.x;
    if (blk < 8192) {
        split8(e_j, ehi, elo, blk * 256 + tid);
    } else if (blk < 8704) {
        split8(Wk, wh, wl, (blk - 8192) * 256 + tid);
    } else {
        int wid  = ((blk - 8704) * 256 + tid) >> 6;   // 0..8191
        int lane = tid & 63;
        int r = wid >> 10;
        int d = wid & (DD - 1);
        const float* x = e_i + (size_t)r * DD;
        const float* w = Wq + (size_t)d * DD;
        float s = 0.f;
        #pragma unroll
        for (int e0 = 0; e0 < DD; e0 += 256) {
            float4 xv = *(const float4*)&x[e0 + lane * 4];
            float4 wv = *(const float4*)&w[e0 + lane * 4];
            s += xv.x * wv.x + xv.y * wv.y + xv.z * wv.z + xv.w * wv.w;
        }
        #pragma unroll
        for (int off = 32; off; off >>= 1) s += __shfl_down(s, off, 64);
        if (lane == 0) q[wid] = s;
    }
}

// ---------------- heavy kernel: bf16x3 MFMA GEMM + fused tanh(q+k)*omega row-reduce
__global__ __launch_bounds__(256) void sigma_mfma(const unsigned short* __restrict__ ehi,
                                                  const unsigned short* __restrict__ elo,
                                                  const unsigned short* __restrict__ wh,
                                                  const unsigned short* __restrict__ wl,
                                                  const float* __restrict__ q,
                                                  const float* __restrict__ omega,
                                                  float* __restrict__ sig_part)   // [8][MM]
{
    __shared__ unsigned short lds[4][128][32];
    __shared__ float red[128][2];

    const int tid  = threadIdx.x;
    const int lane = tid & 63;
    const int w    = tid >> 6;
    const int wr   = w >> 1, wc = w & 1;
    const int c15  = lane & 15, quad = lane >> 4;

    const int row0 = blockIdx.x * 128;
    const int col0 = blockIdx.y * 128;
    const int b    = row0 / NN;

    const int r0 = tid >> 2;
    const int kk = (tid & 3) * 8;

    const unsigned short* ga0 = ehi + (size_t)(row0 + r0) * DD + kk;
    const unsigned short* ga1 = ga0 + (size_t)64 * DD;
    const unsigned short* gb0 = elo + (size_t)(row0 + r0) * DD + kk;
    const unsigned short* gb1 = gb0 + (size_t)64 * DD;
    const unsigned short* gc0 = wh  + (size_t)(col0 + r0) * DD + kk;
    const unsigned short* gc1 = gc0 + (size_t)64 * DD;
    const unsigned short* gd0 = wl  + (size_t)(col0 + r0) * DD + kk;
    const unsigned short* gd1 = gd0 + (size_t)64 * DD;

    char* lbase = (char*)&lds[0][0][0] + w * 1024;

    floatx4 acc[4][4];
    #pragma unroll
    for (int i = 0; i < 4; ++i)
        #pragma unroll
        for (int j = 0; j < 4; ++j)
            acc[i][j] = (floatx4){0.f, 0.f, 0.f, 0.f};

    for (int k0 = 0; k0 < DD; k0 += 32) {
        glds16(ga0 + k0, lbase + 0 * 4096);
        glds16(ga1 + k0, lbase + 1 * 4096);
        glds16(gb0 + k0, lbase + 2 * 4096);
        glds16(gb1 + k0, lbase + 3 * 4096);
        glds16(gc0 + k0, lbase + 4 * 4096);
        glds16(gc1 + k0, lbase + 5 * 4096);
        glds16(gd0 + k0, lbase + 6 * 4096);
        glds16(gd1 + k0, lbase + 7 * 4096);
        __syncthreads();

        short8 ah[4], al[4], bh[4], bl[4];
        #pragma unroll
        for (int i = 0; i < 4; ++i) {
            ah[i] = *(const short8*)&lds[0][wr * 64 + i * 16 + c15][quad * 8];
            al[i] = *(const short8*)&lds[1][wr * 64 + i * 16 + c15][quad * 8];
            bh[i] = *(const short8*)&lds[2][wc * 64 + i * 16 + c15][quad * 8];
            bl[i] = *(const short8*)&lds[3][wc * 64 + i * 16 + c15][quad * 8];
        }
        #pragma unroll
        for (int i = 0; i < 4; ++i)
            #pragma unroll
            for (int j = 0; j < 4; ++j) {
                acc[i][j] = __builtin_amdgcn_mfma_f32_16x16x32_bf16(ah[i], bh[j], acc[i][j], 0, 0, 0);
                acc[i][j] = __builtin_amdgcn_mfma_f32_16x16x32_bf16(al[i], bh[j], acc[i][j], 0, 0, 0);
                acc[i][j] = __builtin_amdgcn_mfma_f32_16x16x32_bf16(ah[i], bl[j], acc[i][j], 0, 0, 0);
            }
        __syncthreads();
    }

    float part[4][4];
    #pragma unroll
    for (int i = 0; i < 4; ++i)
        #pragma unroll
        for (int r = 0; r < 4; ++r) part[i][r] = 0.f;

    #pragma unroll
    for (int j = 0; j < 4; ++j) {
        int c = col0 + wc * 64 + j * 16 + c15;
        float qv = q[b * DD + c];
        float om = omega[c];
        #pragma unroll
        for (int i = 0; i < 4; ++i)
            #pragma unroll
            for (int r = 0; r < 4; ++r)
                part[i][r] += tanhf(acc[i][j][r] + qv) * om;
    }
    #pragma unroll
    for (int i = 0; i < 4; ++i)
        #pragma unroll
        for (int r = 0; r < 4; ++r) {
            float s = part[i][r];
            s += __shfl_xor(s, 1, 64);
            s += __shfl_xor(s, 2, 64);
            s += __shfl_xor(s, 4, 64);
            s += __shfl_xor(s, 8, 64);
            if (c15 == 0) red[wr * 64 + i * 16 + quad * 4 + r][wc] = s;
        }
    __syncthreads();
    if (tid < 128)
        sig_part[blockIdx.y * MM + row0 + tid] = red[tid][0] + red[tid][1];
}

// ---------------- per-b softmax-style weights
__global__ __launch_bounds__(256) void softmax_k(const float* __restrict__ sig_part,
                                                 const float* __restrict__ imp,
                                                 float* __restrict__ a_ij) {
    int b = blockIdx.x;
    int tid = threadIdx.x;
    __shared__ float sbuf[NN];
    __shared__ float red[256];
    float m = -1e30f;
    for (int n = tid; n < NN; n += 256) {
        float s = 0.f;
        #pragma unroll
        for (int db = 0; db < 8; ++db) s += sig_part[db * MM + b * NN + n];
        sbuf[n] = s;
        m = fmaxf(m, s);
    }
    red[tid] = m; __syncthreads();
    for (int off = 128; off; off >>= 1) {
        if (tid < off) red[tid] = fmaxf(red[tid], red[tid + off]);
        __syncthreads();
    }
    m = red[0]; __syncthreads();
    float sum = 0.f;
    for (int n = tid; n < NN; n += 256) sum += expf(sbuf[n] - m);
    red[tid] = sum; __syncthreads();
    for (int off = 128; off; off >>= 1) {
        if (tid < off) red[tid] += red[tid + off];
        __syncthreads();
    }
    sum = red[0];
    float denom = sum + 1e-9f * expf(-m);
    float inv = 1.f / denom;
    for (int n = tid; n < NN; n += 256)
        a_ij[b * NN + n] = imp[b * NN + n] * expf(sbuf[n] - m) * inv;
}

// ---------------- u[b,e] = sum_n a_ij[b,n] * e_j[b,n,e]  — 512 blocks, 32 rows each
__global__ __launch_bounds__(256) void u_kernel(const float* __restrict__ a_ij,
                                                const float* __restrict__ ej,
                                                float* __restrict__ u) {
    int b = blockIdx.x, nc = blockIdx.y;
    int t = threadIdx.x;
    float4 acc = {0.f, 0.f, 0.f, 0.f};
    const float* base = ej + ((size_t)(b * NN + nc * 32)) * DD + t * 4;
    const float* ap = a_ij + b * NN + nc * 32;
    #pragma unroll 4
    for (int n = 0; n < 32; ++n) {
        float a = ap[n];
        float4 v = *(const float4*)(base + (size_t)n * DD);
        acc.x += a * v.x; acc.y += a * v.y; acc.z += a * v.z; acc.w += a * v.w;
    }
    float* up = u + b * DD + t * 4;
    atomicAdd(up + 0, acc.x); atomicAdd(up + 1, acc.y);
    atomicAdd(up + 2, acc.z); atomicAdd(up + 3, acc.w);
}

// ---------------- A = u @ Wv^T
__global__ __launch_bounds__(256) void rowdot_A(const float* __restrict__ X,
                                                const float* __restrict__ W,
                                                float* __restrict__ out) {
    int wid  = (blockIdx.x * blockDim.x + threadIdx.x) >> 6;
    int lane = threadIdx.x & 63;
    int r = wid >> 10;
    int d = wid & (DD - 1);
    const float* x = X + (size_t)r * DD;
    const float* w = W + (size_t)d * DD;
    float s = 0.f;
    #pragma unroll
    for (int e0 = 0; e0 < DD; e0 += 256) {
        float4 xv = *(const float4*)&x[e0 + lane * 4];
        float4 wv = *(const float4*)&w[e0 + lane * 4];
        s += xv.x * wv.x + xv.y * wv.y + xv.z * wv.z + xv.w * wv.w;
    }
    #pragma unroll
    for (int off = 32; off; off >>= 1) s += __shfl_down(s, off, 64);
    if (lane == 0) out[wid] = s;
}

// ---------------- outputs: A, A_lk = A*R, A_l = A
__global__ __launch_bounds__(256) void out_kernel(const float* __restrict__ A,
                                                  const float* __restrict__ Rlk,
                                                  float* __restrict__ out) {
    int i = blockIdx.x * 256 + threadIdx.x;
    int d = i & (DD - 1);
    int l = (i >> 10) & (LL - 1);
    int b = i >> 17;
    out[BB * DD + i] = A[b * DD + d] * Rlk[l * DD + d];
    if (i < BB * DD) {
        out[i] = A[i];
        out[BB * DD + BB * LL * DD + i] = A[i];
    }
}

extern "C" void kernel_launch(void* const* d_in, const int* in_sizes, int n_in,
                              void* d_out, int out_size, void* d_ws, size_t ws_size,
                              hipStream_t stream) {
    const float* e_i   = (const float*)d_in[0];
    const float* e_j   = (const float*)d_in[1];
    const float* imp   = (const float*)d_in[2];
    const float* Rlk   = (const float*)d_in[3];
    const float* Wq    = (const float*)d_in[4];
    const float* Wk    = (const float*)d_in[5];
    const float* Wv    = (const float*)d_in[6];
    const float* omega = (const float*)d_in[7];
    float* out = (float*)d_out;
    float* ws  = (float*)d_ws;

    float* q    = ws;               // 8192
    float* sigp = ws + 8192;        // 131072
    float* a_ij = ws + 139264;      // 16384
    float* u    = ws + 155648;      // 8192
    float* Abuf = ws + 163840;      // 8192
    unsigned short* ehi = (unsigned short*)(ws + 172032);
    unsigned short* elo = ehi + (size_t)MM * DD;
    unsigned short* wh  = elo + (size_t)MM * DD;
    unsigned short* wl  = wh + (size_t)DD * DD;

    hipMemsetAsync(u, 0, BB * DD * sizeof(float), stream);

    // fused preprocessing: split e_j, split Wk, q = e_i @ Wq^T
    prep_kernel<<<10752, 256, 0, stream>>>(e_j, ehi, elo, Wk, wh, wl, e_i, Wq, q);

    // sigma partials: bf16x3 MFMA GEMM with fused tanh-omega reduction
    sigma_mfma<<<dim3(MM / 128, DD / 128), 256, 0, stream>>>(ehi, elo, wh, wl, q, omega, sigp);

    // a_ij
    softmax_k<<<BB, 256, 0, stream>>>(sigp, imp, a_ij);

    // u = a_ij-weighted sum of e_j rows (512 blocks)
    u_kernel<<<dim3(BB, 64), 256, 0, stream>>>(a_ij, e_j, u);

    // A = u @ Wv^T
    rowdot_A<<<2048, 256, 0, stream>>>(u, Wv, Abuf);

    // outputs
    out_kernel<<<(BB * LL * DD) / 256, 256, 0, stream>>>(Abuf, Rlk, out);
}